// Round 5
// baseline (577.544 us; speedup 1.0000x reference)
//
#include <hip/hip_runtime.h>
#include <math.h>

typedef float f32x4 __attribute__((ext_vector_type(4)));

// ---------------------------------------------------------------------------
// Sinusoidal embed + Linear/SiLU x2 + row-broadcast store.
// FP32 inputs, FP32 OUTPUT (512 MB). 2 batches per block, 256 threads.
// out[b,0,i,j] = h2[b,j] for all i  (broadcast along H; verified orientation).
// Weights read directly from global (128 KB total -> L1/L2 resident).
// ---------------------------------------------------------------------------
__global__ __launch_bounds__(256) void k_main(
    const float* __restrict__ t,
    const float* __restrict__ W1, const float* __restrict__ b1,
    const float* __restrict__ W2, const float* __restrict__ b2,
    float* __restrict__ out)
{
    __shared__ float emb[2][128];
    __shared__ float h1[2][128];
    __shared__ float h2[2][128];

    const int tid  = threadIdx.x;
    const int base = blockIdx.x * 2;

    // --- embedding: emb[b] = [sin(t_b*ang_k) k<64, cos(t_b*ang_k) k<64] ---
    // np: freqs = f32(exp_f64(k*log(1000)/63)); ang = f32(2pi*freq);
    //     phase = t_f32 * ang_f32 (f32); sin/cos on the f32 phase.
    if (tid < 128) {
        int b = tid >> 6, k = tid & 63;
        double a   = (double)k * (6.907755278982137 / 63.0);
        float freq = (float)exp(a);
        float ang  = 6.2831853071795865f * freq;
        float ph   = t[base + b] * ang;
        float sv, cv;
        sincosf(ph, &sv, &cv);
        emb[b][k]      = sv;
        emb[b][64 + k] = cv;
    }
    __syncthreads();

    const int b  = tid >> 7;     // wave-uniform: batch of the pair
    const int jj = tid & 127;    // neuron index

    // --- layer 1: h1[b][jj] = silu(b1[jj] + sum_k emb[b][k]*W1[jj,k]) ---
    {
        float acc = b1[jj];
        const float4* e = (const float4*)emb[b];
        const float4* w = (const float4*)(W1 + jj * 128);
        #pragma unroll
        for (int k4 = 0; k4 < 32; ++k4) {
            float4 wv = w[k4], ev = e[k4];
            acc = fmaf(wv.x, ev.x, acc); acc = fmaf(wv.y, ev.y, acc);
            acc = fmaf(wv.z, ev.z, acc); acc = fmaf(wv.w, ev.w, acc);
        }
        acc = acc / (1.0f + expf(-acc));   // SiLU
        h1[b][jj] = acc;
    }
    __syncthreads();

    // --- layer 2: h2[b][jj] = silu(b2[jj] + sum_k h1[b][k]*W2[jj,k]) ---
    {
        float acc = b2[jj];
        const float4* e = (const float4*)h1[b];
        const float4* w = (const float4*)(W2 + jj * 128);
        #pragma unroll
        for (int k4 = 0; k4 < 32; ++k4) {
            float4 wv = w[k4], ev = e[k4];
            acc = fmaf(wv.x, ev.x, acc); acc = fmaf(wv.y, ev.y, acc);
            acc = fmaf(wv.z, ev.z, acc); acc = fmaf(wv.w, ev.w, acc);
        }
        acc = acc / (1.0f + expf(-acc));   // SiLU
        h2[b][jj] = acc;
    }
    __syncthreads();

    // --- broadcast store (f32): tile = 128 rows x 128 f32 = 4096 float4
    // chunks. Thread writes chunks g = c*256+tid, c<16; in-row f32 offset
    // = (g*4) mod 128 = (tid&31)*4, so v is loop-invariant per batch.
    #pragma unroll
    for (int m = 0; m < 2; ++m) {
        f32x4 v = *(const f32x4*)&h2[m][(tid & 31) * 4];
        f32x4* d = (f32x4*)(out + (size_t)(base + m) * 16384);
        #pragma unroll
        for (int c = 0; c < 16; ++c) {
            __builtin_nontemporal_store(v, d + c * 256 + tid);
        }
    }
}

extern "C" void kernel_launch(void* const* d_in, const int* in_sizes, int n_in,
                              void* d_out, int out_size, void* d_ws, size_t ws_size,
                              hipStream_t stream) {
    const float* t  = (const float*)d_in[0];
    const float* W1 = (const float*)d_in[1];
    const float* b1 = (const float*)d_in[2];
    const float* W2 = (const float*)d_in[3];
    const float* b2 = (const float*)d_in[4];
    float* out = (float*)d_out;
    const int B = in_sizes[0];   // 8192

    k_main<<<B / 2, 256, 0, stream>>>(t, W1, b1, W2, b2, out);
}